// Round 9
// baseline (289.822 us; speedup 1.0000x reference)
//
#include <hip/hip_runtime.h>
#include <hip/hip_bf16.h>

#define BATCH 16
#define CCH   512
#define LSEQ  1024
#define NH    8
#define HD    64
#define NG    32
#define CPG   16
#define EPS   1e-5f

typedef __attribute__((ext_vector_type(8))) short short8;
typedef __attribute__((ext_vector_type(4))) float f32x4;
typedef __attribute__((ext_vector_type(16))) float f32x16;
#define MFMA   __builtin_amdgcn_mfma_f32_16x16x32_bf16
#define MFMA32 __builtin_amdgcn_mfma_f32_32x32x16_bf16

__device__ inline short f2bf(float f) {          // RNE, finite inputs only
  unsigned u = __float_as_uint(f);
  u += 0x7FFFu + ((u >> 16) & 1u);
  return (short)(u >> 16);
}

// async global->LDS, 16B per lane; LDS dest is wave-uniform base + lane*16
__device__ inline void gl2lds16(const short* g, short* l) {
  __builtin_amdgcn_global_load_lds(
      (const __attribute__((address_space(1))) unsigned*)g,
      (__attribute__((address_space(3))) unsigned*)l, 16, 0, 0);
}
#define VMCNT0() asm volatile("s_waitcnt vmcnt(0)" ::: "memory")

// ---------------- weight fp32 -> bf16 ---------------------------------------
__global__ __launch_bounds__(256) void cvt_kernel(const float* __restrict__ src,
                                                  short* __restrict__ dst) {
  const int i = blockIdx.x * 256 + threadIdx.x;          // 1 float4 each
  const float4 v = ((const float4*)src)[i];
  short vals[4] = {f2bf(v.x), f2bf(v.y), f2bf(v.z), f2bf(v.w)};
  *(uint2*)(dst + (size_t)i * 4) = *(uint2*)vals;
}

// ---------------- GroupNorm -> hT[b][l][c] bf16 -----------------------------
__global__ __launch_bounds__(256) void gn_kernel(
    const float* __restrict__ x, const float* __restrict__ nw,
    const float* __restrict__ nb, short* __restrict__ hT)
{
  const int g = blockIdx.x, b = blockIdx.y;
  const size_t base = ((size_t)b * CCH + (size_t)g * CPG) * LSEQ;
  const float4* __restrict__ x4 = (const float4*)(x + base);
  const int tid = threadIdx.x;

  __shared__ short T[16][1026];
  __shared__ float red0[4], red1[4];

  float4 v[16];
  float s = 0.f, s2 = 0.f;
#pragma unroll
  for (int r = 0; r < 16; ++r) {
    v[r] = x4[tid + 256 * r];
    s  += (v[r].x + v[r].y) + (v[r].z + v[r].w);
    s2 += (v[r].x * v[r].x + v[r].y * v[r].y) + (v[r].z * v[r].z + v[r].w * v[r].w);
  }
#pragma unroll
  for (int m = 1; m < 64; m <<= 1) { s += __shfl_xor(s, m); s2 += __shfl_xor(s2, m); }
  const int wid = tid >> 6;
  if ((tid & 63) == 0) { red0[wid] = s; red1[wid] = s2; }
  __syncthreads();
  const float ts  = (red0[0] + red0[1]) + (red0[2] + red0[3]);
  const float ts2 = (red1[0] + red1[1]) + (red1[2] + red1[3]);
  const float mean = ts * (1.f / 16384.f);
  const float var  = ts2 * (1.f / 16384.f) - mean * mean;
  const float rstd = rsqrtf(var + EPS);
#pragma unroll
  for (int r = 0; r < 16; ++r) {
    const int e = tid + 256 * r;
    const int c = e >> 8, l4 = (e & 255) * 4;
    const float sc = rstd * nw[g * CPG + c];
    const float sh = nb[g * CPG + c] - mean * sc;
    T[c][l4 + 0] = f2bf(v[r].x * sc + sh);
    T[c][l4 + 1] = f2bf(v[r].y * sc + sh);
    T[c][l4 + 2] = f2bf(v[r].z * sc + sh);
    T[c][l4 + 3] = f2bf(v[r].w * sc + sh);
  }
  __syncthreads();
  short* __restrict__ outp = hT + (size_t)b * LSEQ * CCH + g * CPG;
#pragma unroll
  for (int it = 0; it < 4; ++it) {
    const int l = tid + 256 * it;
    short vals[16];
#pragma unroll
    for (int c = 0; c < 16; ++c) vals[c] = T[c][l];
    *(short8*)(outp + (size_t)l * CCH)     = *(short8*)&vals[0];
    *(short8*)(outp + (size_t)l * CCH + 8) = *(short8*)&vals[8];
  }
}

// ---------------- QKV GEMM (bf16 MFMA, gl_lds 2-phase dbuf) -----------------
// Q region is scaled by hd^-0.5 * log2(e) so attention works in exp2 domain.
__global__ __launch_bounds__(256) void qkv_gemm(
    const short* __restrict__ Wb, const float* __restrict__ bias,
    const short* __restrict__ hT, short* __restrict__ qT,
    short* __restrict__ kT, short* __restrict__ vv)
{
  const int b = blockIdx.z, my = blockIdx.y;
  const int m0 = my * 128, n0 = blockIdx.x * 128;
  const short* __restrict__ Bsrc = hT + (size_t)b * LSEQ * CCH;

  __shared__ short smem[32768];            // [A:2x128x64][B:2x128x64] = 64KB
  const int tid = threadIdx.x, lane = tid & 63, w = tid >> 6;
  const int wm = (w >> 1) * 64, wn = (w & 1) * 64;
  const int l15 = lane & 15, l4g = lane >> 4;
  const int sr = lane >> 3, c8 = ((lane & 7) ^ (lane >> 3)) * 8;
  const int swz = (l15 & 7) << 4;

  const f32x4 fz = {0.f, 0.f, 0.f, 0.f};
  f32x4 acc[4][4];
#pragma unroll
  for (int i = 0; i < 4; ++i)
#pragma unroll
    for (int j = 0; j < 4; ++j) acc[i][j] = fz;

#define QSTAGE(ks, bb)                                                        \
  {                                                                           \
    const int k0_ = (ks) * 64;                                                \
    _Pragma("unroll")                                                         \
    for (int i_ = 0; i_ < 4; ++i_) {                                          \
      const int rb_ = w * 32 + i_ * 8;                                        \
      gl2lds16(Wb   + (size_t)(m0 + rb_ + sr) * CCH + k0_ + c8,               \
               &smem[(bb) * 8192 + rb_ * 64]);                                \
      gl2lds16(Bsrc + (size_t)(n0 + rb_ + sr) * CCH + k0_ + c8,               \
               &smem[16384 + (bb) * 8192 + rb_ * 64]);                        \
    }                                                                         \
  }

  QSTAGE(0, 0);
  VMCNT0();
  __syncthreads();

  for (int ks = 0; ks < 8; ++ks) {
    const int bb = ks & 1;
    if (ks < 7) QSTAGE(ks + 1, bb ^ 1);
#pragma unroll
    for (int kk = 0; kk < 2; ++kk) {
      const int ko = (kk * 64 + l4g * 16) ^ swz;
      short8 af[4], bf[4];
#pragma unroll
      for (int i = 0; i < 4; ++i)
        af[i] = *(const short8*)((const char*)&smem[bb * 8192 + (wm + i * 16 + l15) * 64] + ko);
#pragma unroll
      for (int j = 0; j < 4; ++j)
        bf[j] = *(const short8*)((const char*)&smem[16384 + bb * 8192 + (wn + j * 16 + l15) * 64] + ko);
#pragma unroll
      for (int i = 0; i < 4; ++i)
#pragma unroll
        for (int j = 0; j < 4; ++j)
          acc[i][j] = MFMA(af[i], bf[j], acc[i][j], 0, 0, 0);
    }
    VMCNT0();
    __syncthreads();
  }

  const int region = my >> 2;                      // 0=Q 1=K 2=V
  const float scale = (region == 0) ? 0.125f * 1.44269504f : 1.0f;
  short (*CT)[136] = (short (*)[136])smem;         // 128x136 = 17408 < 32768

#pragma unroll
  for (int i = 0; i < 4; ++i)
#pragma unroll
    for (int r = 0; r < 4; ++r) {
      const int cl = wm + i * 16 + l4g * 4 + r;    // channel within 128-tile
      const float bb = bias[m0 + cl];
#pragma unroll
      for (int j = 0; j < 4; ++j) {
        const int ll = wn + j * 16 + l15;          // l within 128-tile
        const short bv = f2bf((acc[i][j][r] + bb) * scale);
        if (region == 2) CT[cl][ll] = bv; else CT[ll][cl] = bv;
      }
    }
  __syncthreads();
#pragma unroll
  for (int it = 0; it < 8; ++it) {
    const int f = tid + it * 256;
    const int rr = f >> 4, cc8 = (f & 15) * 8;
    const short8 val = *(const short8*)&CT[rr][cc8];
    if (region == 2) {
      *(short8*)(vv + (size_t)b * CCH * LSEQ + (size_t)((my & 3) * 128 + rr) * LSEQ + n0 + cc8) = val;
    } else {
      short* __restrict__ dst = (region == 0) ? qT : kT;
      *(short8*)(dst + (size_t)b * LSEQ * CCH + (size_t)(n0 + rr) * CCH + (my & 3) * 128 + cc8) = val;
    }
  }
}

// ---------------- flash attention: 32x32 MFMA, double-swapped ---------------
// S' = K.Q^T and O' = V^T.P^T so q = lane&31 in BOTH C-layouts: softmax and
// rescale are lane-local (1 shfl_xor(32) per reduce, zero broadcasts).
// Wave owns 32 q-rows; block = 128 q. XCD-swizzled block decode for K/V L2.
__global__ __launch_bounds__(256) void attn_kernel(
    const short* __restrict__ qT, const short* __restrict__ kT,
    const short* __restrict__ vv, short* __restrict__ oT)
{
  const int id = blockIdx.x;
  const int qt = id >> 7, bhh = id & 127;          // same (b,hh) => same XCD
  const int hh = bhh & 7, b = bhh >> 3;
  const int l0 = qt * 128, h64 = hh * 64;
  const int tid = threadIdx.x, lane = tid & 63, w = tid >> 6;
  const int l31 = lane & 31, hi = lane >> 5;
  const int wq = w * 32;

  __shared__ short Ks[2][64][64];
  __shared__ short Vs[2][64][64];

  const short* __restrict__ qb = qT + (size_t)b * LSEQ * CCH;
  const short* __restrict__ kb = kT + (size_t)b * LSEQ * CCH;
  const short* __restrict__ vb = vv + (size_t)b * CCH * LSEQ;

  // Q as B-frag per k-step t: col q=l31, k = t*16 + hi*8 + e
  short8 qf[4];
#pragma unroll
  for (int t = 0; t < 4; ++t)
    qf[t] = *(const short8*)(qb + (size_t)(l0 + wq + l31) * CCH + h64 + t * 16 + hi * 8);

  f32x16 oacc0 = {0.f,0.f,0.f,0.f,0.f,0.f,0.f,0.f,0.f,0.f,0.f,0.f,0.f,0.f,0.f,0.f};
  f32x16 oacc1 = oacc0;
  float mr = -1.0e30f, lr = 0.f;                   // state for q = wq + l31

  const int sr = lane >> 3, c8 = ((lane & 7) ^ (lane >> 3)) * 8;

#define ASTAGE(jt_, bb)                                                       \
  {                                                                           \
    const int j0_ = (jt_) * 64;                                               \
    _Pragma("unroll")                                                         \
    for (int i_ = 0; i_ < 2; ++i_) {                                          \
      const int rb_ = w * 16 + i_ * 8;                                        \
      gl2lds16(kb + (size_t)(j0_ + rb_ + sr) * CCH + h64 + c8,                \
               &Ks[bb][rb_][0]);                                              \
      gl2lds16(vb + (size_t)(h64 + rb_ + sr) * LSEQ + j0_ + c8,               \
               &Vs[bb][rb_][0]);                                              \
    }                                                                         \
  }

  ASTAGE(0, 0);
  VMCNT0();
  __syncthreads();

  for (int jt = 0; jt < 16; ++jt) {
    const int bb = jt & 1;
    if (jt < 15) ASTAGE(jt + 1, bb ^ 1);

    // ---- S' = K.Q^T : lane holds S[kv=(r&3)+8*(r>>2)+4*hi (+32n)][q=l31]
    f32x16 s0 = {0.f,0.f,0.f,0.f,0.f,0.f,0.f,0.f,0.f,0.f,0.f,0.f,0.f,0.f,0.f,0.f};
    f32x16 s1 = s0;
#pragma unroll
    for (int t = 0; t < 4; ++t) {
      const int byt = ((t * 2 + hi) ^ (l31 & 7)) * 16;
      const short8 k0 = *(const short8*)((const char*)&Ks[bb][l31][0] + byt);
      const short8 k1 = *(const short8*)((const char*)&Ks[bb][32 + l31][0] + byt);
      s0 = MFMA32(k0, qf[t], s0, 0, 0, 0);
      s1 = MFMA32(k1, qf[t], s1, 0, 0, 0);
    }

    // ---- online softmax (exp2 domain), all lane-local for q=l31
    float t16[16];
#pragma unroll
    for (int i = 0; i < 16; ++i) t16[i] = fmaxf(s0[i], s1[i]);
#pragma unroll
    for (int st = 8; st > 0; st >>= 1)
#pragma unroll
      for (int i = 0; i < 8; ++i)
        if (i < st) t16[i] = fmaxf(t16[i], t16[i + st]);
    float mx = t16[0];
    mx = fmaxf(mx, __shfl_xor(mx, 32));
    const float mnew = fmaxf(mr, mx);
    const float corr = exp2f(mr - mnew);
    mr = mnew;

#pragma unroll
    for (int i = 0; i < 16; ++i) {
      s0[i] = exp2f(s0[i] - mnew);
      s1[i] = exp2f(s1[i] - mnew);
    }
    float a16[16];
#pragma unroll
    for (int i = 0; i < 16; ++i) a16[i] = s0[i] + s1[i];
#pragma unroll
    for (int st = 8; st > 0; st >>= 1)
#pragma unroll
      for (int i = 0; i < 8; ++i)
        if (i < st) a16[i] += a16[i + st];
    float rs = a16[0];
    rs += __shfl_xor(rs, 32);
    lr = lr * corr + rs;

    // ---- pack P to bf16 pairs: wpk[n*8+j] = (p[2j], p[2j+1]) of subtile n
    unsigned wpk[16];
#pragma unroll
    for (int j = 0; j < 8; ++j) {
      __hip_bfloat162 pa = __float22bfloat162_rn(make_float2(s0[2 * j], s0[2 * j + 1]));
      __hip_bfloat162 pb = __float22bfloat162_rn(make_float2(s1[2 * j], s1[2 * j + 1]));
      wpk[j]     = *(unsigned*)&pa;
      wpk[8 + j] = *(unsigned*)&pb;
    }

    // ---- rescale O (corr is lane-local: O col = q = l31)
#pragma unroll
    for (int i = 0; i < 16; ++i) { oacc0[i] *= corr; oacc1[i] *= corr; }

    // ---- O' += V^T.P^T : per kt, rebuild P B-frag via lane-half exchange
#pragma unroll
    for (int kt = 0; kt < 4; ++kt) {
      const int jb = (kt >> 1) * 8 + (kt & 1) * 4;
      const unsigned vs0 = hi ? wpk[jb + 0] : wpk[jb + 2];
      const unsigned vs1 = hi ? wpk[jb + 1] : wpk[jb + 3];
      const unsigned r0 = (unsigned)__shfl_xor((int)vs0, 32);
      const unsigned r1 = (unsigned)__shfl_xor((int)vs1, 32);
      union { unsigned u[4]; short8 s; } pf;
      pf.u[0] = hi ? r0 : wpk[jb + 0];
      pf.u[1] = hi ? r1 : wpk[jb + 1];
      pf.u[2] = hi ? wpk[jb + 2] : r0;
      pf.u[3] = hi ? wpk[jb + 3] : r1;
      const int byt = ((kt * 2 + hi) ^ (l31 & 7)) * 16;
      const short8 v0 = *(const short8*)((const char*)&Vs[bb][l31][0] + byt);
      const short8 v1 = *(const short8*)((const char*)&Vs[bb][32 + l31][0] + byt);
      oacc0 = MFMA32(v0, pf.s, oacc0, 0, 0, 0);
      oacc1 = MFMA32(v1, pf.s, oacc1, 0, 0, 0);
    }
    VMCNT0();
    __syncthreads();
  }

  // ---- finalize: O[d=(r&3)+8*(r>>2)+4hi+32dt][q=l31], l lane-local
  const float lb = 1.f / lr;
  short* __restrict__ ob = oT + (size_t)b * LSEQ * CCH + (size_t)(l0 + wq + l31) * CCH + h64;
#pragma unroll
  for (int rg = 0; rg < 4; ++rg) {
    __hip_bfloat162 w0 = __float22bfloat162_rn(
        make_float2(oacc0[rg * 4 + 0] * lb, oacc0[rg * 4 + 1] * lb));
    __hip_bfloat162 w1 = __float22bfloat162_rn(
        make_float2(oacc0[rg * 4 + 2] * lb, oacc0[rg * 4 + 3] * lb));
    uint2 pk0 = make_uint2(*(unsigned*)&w0, *(unsigned*)&w1);
    *(uint2*)(ob + rg * 8 + hi * 4) = pk0;
    __hip_bfloat162 w2 = __float22bfloat162_rn(
        make_float2(oacc1[rg * 4 + 0] * lb, oacc1[rg * 4 + 1] * lb));
    __hip_bfloat162 w3 = __float22bfloat162_rn(
        make_float2(oacc1[rg * 4 + 2] * lb, oacc1[rg * 4 + 3] * lb));
    uint2 pk1 = make_uint2(*(unsigned*)&w2, *(unsigned*)&w3);
    *(uint2*)(ob + 32 + rg * 8 + hi * 4) = pk1;
  }
}

// ---------------- proj GEMM + bias + residual -> fp32 out -------------------
__global__ __launch_bounds__(256) void proj_gemm(
    const short* __restrict__ Wb, const float* __restrict__ bias,
    const short* __restrict__ oT, const float* __restrict__ x,
    float* __restrict__ out)
{
  const int b = blockIdx.z;
  const int m0 = blockIdx.y * 128, n0 = blockIdx.x * 128;
  const short* __restrict__ Bsrc = oT + (size_t)b * LSEQ * CCH;

  __shared__ short smem[32768];
  const int tid = threadIdx.x, lane = tid & 63, w = tid >> 6;
  const int wm = (w >> 1) * 64, wn = (w & 1) * 64;
  const int l15 = lane & 15, l4g = lane >> 4;
  const int sr = lane >> 3, c8 = ((lane & 7) ^ (lane >> 3)) * 8;
  const int swz = (l15 & 7) << 4;

  const f32x4 fz = {0.f, 0.f, 0.f, 0.f};
  f32x4 acc[4][4];
#pragma unroll
  for (int i = 0; i < 4; ++i)
#pragma unroll
    for (int j = 0; j < 4; ++j) acc[i][j] = fz;

#define PSTAGE(ks, bb)                                                        \
  {                                                                           \
    const int k0_ = (ks) * 64;                                                \
    _Pragma("unroll")                                                         \
    for (int i_ = 0; i_ < 4; ++i_) {                                          \
      const int rb_ = w * 32 + i_ * 8;                                        \
      gl2lds16(Wb   + (size_t)(m0 + rb_ + sr) * CCH + k0_ + c8,               \
               &smem[(bb) * 8192 + rb_ * 64]);                                \
      gl2lds16(Bsrc + (size_t)(n0 + rb_ + sr) * CCH + k0_ + c8,               \
               &smem[16384 + (bb) * 8192 + rb_ * 64]);                        \
    }                                                                         \
  }

  PSTAGE(0, 0);
  VMCNT0();
  __syncthreads();

  for (int ks = 0; ks < 8; ++ks) {
    const int bb = ks & 1;
    if (ks < 7) PSTAGE(ks + 1, bb ^ 1);
#pragma unroll
    for (int kk = 0; kk < 2; ++kk) {
      const int ko = (kk * 64 + l4g * 16) ^ swz;
      short8 af[4], bf[4];
#pragma unroll
      for (int i = 0; i < 4; ++i)
        af[i] = *(const short8*)((const char*)&smem[bb * 8192 + (wm + i * 16 + l15) * 64] + ko);
#pragma unroll
      for (int j = 0; j < 4; ++j)
        bf[j] = *(const short8*)((const char*)&smem[16384 + bb * 8192 + (wn + j * 16 + l15) * 64] + ko);
#pragma unroll
      for (int i = 0; i < 4; ++i)
#pragma unroll
        for (int j = 0; j < 4; ++j)
          acc[i][j] = MFMA(af[i], bf[j], acc[i][j], 0, 0, 0);
    }
    VMCNT0();
    __syncthreads();
  }

  const size_t obase = (size_t)b * CCH * LSEQ;
#pragma unroll
  for (int i = 0; i < 4; ++i)
#pragma unroll
    for (int r = 0; r < 4; ++r) {
      const int gm = m0 + wm + i * 16 + l4g * 4 + r;
      const float bb = bias[gm];
#pragma unroll
      for (int j = 0; j < 4; ++j) {
        const int gl = n0 + wn + j * 16 + l15;
        const size_t idx = obase + (size_t)gm * LSEQ + gl;
        out[idx] = acc[i][j][r] + bb + x[idx];
      }
    }
}

// ---------------------------------------------------------------------------
extern "C" void kernel_launch(void* const* d_in, const int* in_sizes, int n_in,
                              void* d_out, int out_size, void* d_ws, size_t ws_size,
                              hipStream_t stream)
{
  const float* x      = (const float*)d_in[0];
  const float* norm_w = (const float*)d_in[1];
  const float* norm_b = (const float*)d_in[2];
  const float* qkv_w  = (const float*)d_in[3];
  const float* qkv_b  = (const float*)d_in[4];
  const float* proj_w = (const float*)d_in[5];
  const float* proj_b = (const float*)d_in[6];
  float* out = (float*)d_out;

  char* ws = (char*)d_ws;
  short* wq16 = (short*)ws;                                   // 1536*512*2 = 1.5M
  short* wp16 = (short*)(ws + 1572864);                       // 512*512*2  = 0.5M
  short* hT   = (short*)(ws + 2097152);                       // 16M
  short* qT   = (short*)(ws + 2097152 + 16777216);            // 16M
  short* kT   = (short*)(ws + 2097152 + 2 * 16777216);        // 16M
  short* vv   = (short*)(ws + 2097152 + 3 * 16777216);        // 16M
  short* oT   = (short*)(ws + 2097152 + 4 * 16777216);        // 16M

  cvt_kernel<<<768, 256, 0, stream>>>(qkv_w, wq16);
  cvt_kernel<<<256, 256, 0, stream>>>(proj_w, wp16);
  gn_kernel<<<dim3(NG, BATCH), 256, 0, stream>>>(x, norm_w, norm_b, hT);
  qkv_gemm<<<dim3(8, 12, BATCH), 256, 0, stream>>>(wq16, qkv_b, hT, qT, kT, vv);
  attn_kernel<<<1024, 256, 0, stream>>>(qT, kT, vv, oT);
  proj_gemm<<<dim3(8, 4, BATCH), 256, 0, stream>>>(wp16, proj_b, oT, x, out);
}

// Round 10
// 244.403 us; speedup vs baseline: 1.1858x; 1.1858x over previous
//
#include <hip/hip_runtime.h>
#include <hip/hip_bf16.h>

#define BATCH 16
#define CCH   512
#define LSEQ  1024
#define NH    8
#define HD    64
#define NG    32
#define CPG   16
#define EPS   1e-5f

typedef __attribute__((ext_vector_type(8))) short short8;
typedef __attribute__((ext_vector_type(4))) float f32x4;
#define MFMA __builtin_amdgcn_mfma_f32_16x16x32_bf16

__device__ inline short f2bf(float f) {          // RNE, finite inputs only
  unsigned u = __float_as_uint(f);
  u += 0x7FFFu + ((u >> 16) & 1u);
  return (short)(u >> 16);
}

// async global->LDS, 16B per lane; LDS dest is wave-uniform base + lane*16
__device__ inline void gl2lds16(const short* g, short* l) {
  __builtin_amdgcn_global_load_lds(
      (const __attribute__((address_space(1))) unsigned*)g,
      (__attribute__((address_space(3))) unsigned*)l, 16, 0, 0);
}
#define VMCNT0() asm volatile("s_waitcnt vmcnt(0)" ::: "memory")

// ---------------- weight fp32 -> bf16 ---------------------------------------
__global__ __launch_bounds__(256) void cvt_kernel(const float* __restrict__ src,
                                                  short* __restrict__ dst) {
  const int i = blockIdx.x * 256 + threadIdx.x;          // 1 float4 each
  const float4 v = ((const float4*)src)[i];
  short vals[4] = {f2bf(v.x), f2bf(v.y), f2bf(v.z), f2bf(v.w)};
  *(uint2*)(dst + (size_t)i * 4) = *(uint2*)vals;
}

// ---------------- GroupNorm -> hT[b][l][c] bf16 -----------------------------
__global__ __launch_bounds__(256) void gn_kernel(
    const float* __restrict__ x, const float* __restrict__ nw,
    const float* __restrict__ nb, short* __restrict__ hT)
{
  const int g = blockIdx.x, b = blockIdx.y;
  const size_t base = ((size_t)b * CCH + (size_t)g * CPG) * LSEQ;
  const float4* __restrict__ x4 = (const float4*)(x + base);
  const int tid = threadIdx.x;

  __shared__ short T[16][1026];
  __shared__ float red0[4], red1[4];

  float4 v[16];
  float s = 0.f, s2 = 0.f;
#pragma unroll
  for (int r = 0; r < 16; ++r) {
    v[r] = x4[tid + 256 * r];
    s  += (v[r].x + v[r].y) + (v[r].z + v[r].w);
    s2 += (v[r].x * v[r].x + v[r].y * v[r].y) + (v[r].z * v[r].z + v[r].w * v[r].w);
  }
#pragma unroll
  for (int m = 1; m < 64; m <<= 1) { s += __shfl_xor(s, m); s2 += __shfl_xor(s2, m); }
  const int wid = tid >> 6;
  if ((tid & 63) == 0) { red0[wid] = s; red1[wid] = s2; }
  __syncthreads();
  const float ts  = (red0[0] + red0[1]) + (red0[2] + red0[3]);
  const float ts2 = (red1[0] + red1[1]) + (red1[2] + red1[3]);
  const float mean = ts * (1.f / 16384.f);
  const float var  = ts2 * (1.f / 16384.f) - mean * mean;
  const float rstd = rsqrtf(var + EPS);
#pragma unroll
  for (int r = 0; r < 16; ++r) {
    const int e = tid + 256 * r;
    const int c = e >> 8, l4 = (e & 255) * 4;
    const float sc = rstd * nw[g * CPG + c];
    const float sh = nb[g * CPG + c] - mean * sc;
    T[c][l4 + 0] = f2bf(v[r].x * sc + sh);
    T[c][l4 + 1] = f2bf(v[r].y * sc + sh);
    T[c][l4 + 2] = f2bf(v[r].z * sc + sh);
    T[c][l4 + 3] = f2bf(v[r].w * sc + sh);
  }
  __syncthreads();
  short* __restrict__ outp = hT + (size_t)b * LSEQ * CCH + g * CPG;
#pragma unroll
  for (int it = 0; it < 4; ++it) {
    const int l = tid + 256 * it;
    short vals[16];
#pragma unroll
    for (int c = 0; c < 16; ++c) vals[c] = T[c][l];
    *(short8*)(outp + (size_t)l * CCH)     = *(short8*)&vals[0];
    *(short8*)(outp + (size_t)l * CCH + 8) = *(short8*)&vals[8];
  }
}

// ---------------- QKV GEMM (bf16 MFMA, gl_lds 2-phase dbuf) -----------------
// Q region is scaled by hd^-0.5 * log2(e) so attention works in exp2 domain.
__global__ __launch_bounds__(256) void qkv_gemm(
    const short* __restrict__ Wb, const float* __restrict__ bias,
    const short* __restrict__ hT, short* __restrict__ qT,
    short* __restrict__ kT, short* __restrict__ vv)
{
  const int b = blockIdx.z, my = blockIdx.y;
  const int m0 = my * 128, n0 = blockIdx.x * 128;
  const short* __restrict__ Bsrc = hT + (size_t)b * LSEQ * CCH;

  __shared__ short smem[32768];            // [A:2x128x64][B:2x128x64] = 64KB
  const int tid = threadIdx.x, lane = tid & 63, w = tid >> 6;
  const int wm = (w >> 1) * 64, wn = (w & 1) * 64;
  const int l15 = lane & 15, l4g = lane >> 4;
  const int sr = lane >> 3, c8 = ((lane & 7) ^ (lane >> 3)) * 8;
  const int swz = (l15 & 7) << 4;

  const f32x4 fz = {0.f, 0.f, 0.f, 0.f};
  f32x4 acc[4][4];
#pragma unroll
  for (int i = 0; i < 4; ++i)
#pragma unroll
    for (int j = 0; j < 4; ++j) acc[i][j] = fz;

#define QSTAGE(ks, bb)                                                        \
  {                                                                           \
    const int k0_ = (ks) * 64;                                                \
    _Pragma("unroll")                                                         \
    for (int i_ = 0; i_ < 4; ++i_) {                                          \
      const int rb_ = w * 32 + i_ * 8;                                        \
      gl2lds16(Wb   + (size_t)(m0 + rb_ + sr) * CCH + k0_ + c8,               \
               &smem[(bb) * 8192 + rb_ * 64]);                                \
      gl2lds16(Bsrc + (size_t)(n0 + rb_ + sr) * CCH + k0_ + c8,               \
               &smem[16384 + (bb) * 8192 + rb_ * 64]);                        \
    }                                                                         \
  }

  QSTAGE(0, 0);
  VMCNT0();
  __syncthreads();

  for (int ks = 0; ks < 8; ++ks) {
    const int bb = ks & 1;
    if (ks < 7) QSTAGE(ks + 1, bb ^ 1);
#pragma unroll
    for (int kk = 0; kk < 2; ++kk) {
      const int ko = (kk * 64 + l4g * 16) ^ swz;
      short8 af[4], bf[4];
#pragma unroll
      for (int i = 0; i < 4; ++i)
        af[i] = *(const short8*)((const char*)&smem[bb * 8192 + (wm + i * 16 + l15) * 64] + ko);
#pragma unroll
      for (int j = 0; j < 4; ++j)
        bf[j] = *(const short8*)((const char*)&smem[16384 + bb * 8192 + (wn + j * 16 + l15) * 64] + ko);
#pragma unroll
      for (int i = 0; i < 4; ++i)
#pragma unroll
        for (int j = 0; j < 4; ++j)
          acc[i][j] = MFMA(af[i], bf[j], acc[i][j], 0, 0, 0);
    }
    VMCNT0();
    __syncthreads();
  }

  const int region = my >> 2;                      // 0=Q 1=K 2=V
  const float scale = (region == 0) ? 0.125f * 1.44269504f : 1.0f;
  short (*CT)[136] = (short (*)[136])smem;         // 128x136 = 17408 < 32768

#pragma unroll
  for (int i = 0; i < 4; ++i)
#pragma unroll
    for (int r = 0; r < 4; ++r) {
      const int cl = wm + i * 16 + l4g * 4 + r;    // channel within 128-tile
      const float bb = bias[m0 + cl];
#pragma unroll
      for (int j = 0; j < 4; ++j) {
        const int ll = wn + j * 16 + l15;          // l within 128-tile
        const short bv = f2bf((acc[i][j][r] + bb) * scale);
        if (region == 2) CT[cl][ll] = bv; else CT[ll][cl] = bv;
      }
    }
  __syncthreads();
#pragma unroll
  for (int it = 0; it < 8; ++it) {
    const int f = tid + it * 256;
    const int rr = f >> 4, cc8 = (f & 15) * 8;
    const short8 val = *(const short8*)&CT[rr][cc8];
    if (region == 2) {
      *(short8*)(vv + (size_t)b * CCH * LSEQ + (size_t)((my & 3) * 128 + rr) * LSEQ + n0 + cc8) = val;
    } else {
      short* __restrict__ dst = (region == 0) ? qT : kT;
      *(short8*)(dst + (size_t)b * LSEQ * CCH + (size_t)(n0 + rr) * CCH + (my & 3) * 128 + cc8) = val;
    }
  }
}

// ---------------- flash attention, swapped-QK^T + gl_lds dbuf ---------------
// Round-7 structure (16x16, 72 VGPR, 28% occ) + XCD-swizzled block decode
// (validated: FETCH 139->50 MB) + exp2-domain softmax (Q pre-scaled by log2e).
__global__ __launch_bounds__(256) void attn_kernel(
    const short* __restrict__ qT, const short* __restrict__ kT,
    const short* __restrict__ vv, short* __restrict__ oT)
{
  const int id = blockIdx.x;
  const int qt = id >> 7, bhh = id & 127;          // 128 = 0 mod 8: same (b,hh)
  const int hh = bhh & 7, b = bhh >> 3;            // blocks share one XCD's L2
  const int l0 = qt * 64, h64 = hh * 64;
  const int tid = threadIdx.x, lane = tid & 63, w = tid >> 6;
  const int l15 = lane & 15, l4g = lane >> 4;
  const int wq = w * 16;

  __shared__ short Ks[2][64][64];
  __shared__ short Vs[2][64][64];
  __shared__ unsigned Pw[4][16][36];   // [wave][q][u32 word]

  const short* __restrict__ qb = qT + (size_t)b * LSEQ * CCH;
  const short* __restrict__ kb = kT + (size_t)b * LSEQ * CCH;
  const short* __restrict__ vb = vv + (size_t)b * CCH * LSEQ;

  // Q as B-operand: B[n=q=l15][k=c], 8 contiguous c per lane
  short8 qf[2];
#pragma unroll
  for (int kk = 0; kk < 2; ++kk)
    qf[kk] = *(const short8*)(qb + (size_t)(l0 + wq + l15) * CCH + h64 + kk * 32 + l4g * 8);

  const f32x4 fz = {0.f, 0.f, 0.f, 0.f};
  f32x4 o[4];                          // O[q=l4g*4+r][d=df*16+l15]
#pragma unroll
  for (int df = 0; df < 4; ++df) o[df] = fz;
  float mr = -1.0e30f, lr = 0.f;       // state for q = l15

  const int sr = lane >> 3, c8 = ((lane & 7) ^ (lane >> 3)) * 8;
  const int swz = (l15 & 7) << 4;

#define ASTAGE(jt_, bb)                                                       \
  {                                                                           \
    const int j0_ = (jt_) * 64;                                               \
    _Pragma("unroll")                                                         \
    for (int i_ = 0; i_ < 2; ++i_) {                                          \
      const int rb_ = w * 16 + i_ * 8;                                        \
      gl2lds16(kb + (size_t)(j0_ + rb_ + sr) * CCH + h64 + c8,                \
               &Ks[bb][rb_][0]);                                              \
      gl2lds16(vb + (size_t)(h64 + rb_ + sr) * LSEQ + j0_ + c8,               \
               &Vs[bb][rb_][0]);                                              \
    }                                                                         \
  }

  ASTAGE(0, 0);
  VMCNT0();
  __syncthreads();

  for (int jt = 0; jt < 16; ++jt) {
    const int bb = jt & 1;
    if (jt < 15) ASTAGE(jt + 1, bb ^ 1);

    // S' = K.Q^T : s[j] rows kv=j*16+l4g*4+r, col q=l15
    f32x4 s[4];
#pragma unroll
    for (int j = 0; j < 4; ++j) s[j] = fz;
#pragma unroll
    for (int kk = 0; kk < 2; ++kk) {
      const int ko = (kk * 64 + l4g * 16) ^ swz;
      short8 kf[4];
#pragma unroll
      for (int j = 0; j < 4; ++j)
        kf[j] = *(const short8*)((const char*)&Ks[bb][j * 16 + l15][0] + ko);
#pragma unroll
      for (int j = 0; j < 4; ++j) s[j] = MFMA(kf[j], qf[kk], s[j], 0, 0, 0);
    }

    // online softmax for q=l15 (64 kv values: 16 in-reg x 4 lane-groups)
    float mx = s[0][0];
#pragma unroll
    for (int j = 0; j < 4; ++j)
#pragma unroll
      for (int r = 0; r < 4; ++r) mx = fmaxf(mx, s[j][r]);
    mx = fmaxf(mx, __shfl_xor(mx, 16));
    mx = fmaxf(mx, __shfl_xor(mx, 32));
    const float mnew = fmaxf(mr, mx);
    const float corr = exp2f(mr - mnew);
    mr = mnew;

    float rs = 0.f;
    unsigned pk[4][2];
#pragma unroll
    for (int j = 0; j < 4; ++j) {
      float p0 = exp2f(s[j][0] - mnew), p1 = exp2f(s[j][1] - mnew);
      float p2 = exp2f(s[j][2] - mnew), p3 = exp2f(s[j][3] - mnew);
      rs += (p0 + p1) + (p2 + p3);
      __hip_bfloat162 w0 = __float22bfloat162_rn(make_float2(p0, p1));
      __hip_bfloat162 w1 = __float22bfloat162_rn(make_float2(p2, p3));
      pk[j][0] = *(unsigned*)&w0;
      pk[j][1] = *(unsigned*)&w1;
    }
    rs += __shfl_xor(rs, 16);
    rs += __shfl_xor(rs, 32);
    lr = lr * corr + rs;

    // P -> own-wave LDS stripe
#pragma unroll
    for (int j = 0; j < 4; ++j)
      *(uint2*)&Pw[w][l15][j * 8 + l4g * 2] = make_uint2(pk[j][0], pk[j][1]);

    // rescale O: lane's O rows are q = l4g*4+r
    float cb[4];
#pragma unroll
    for (int r = 0; r < 4; ++r) cb[r] = __shfl(corr, l4g * 4 + r);
#pragma unroll
    for (int df = 0; df < 4; ++df)
#pragma unroll
      for (int r = 0; r < 4; ++r) o[df][r] *= cb[r];

    // O += P.V  (A-frag from Pw: row q=l15, kv = kk*32 + l4g*8 .. +8)
#pragma unroll
    for (int kk = 0; kk < 2; ++kk) {
      const short8 pf = *(const short8*)&Pw[w][l15][kk * 16 + l4g * 4];
      const int ko = (kk * 64 + l4g * 16) ^ swz;
#pragma unroll
      for (int df = 0; df < 4; ++df) {
        const short8 vf = *(const short8*)((const char*)&Vs[bb][df * 16 + l15][0] + ko);
        o[df] = MFMA(pf, vf, o[df], 0, 0, 0);
      }
    }
    VMCNT0();
    __syncthreads();
  }

  // finalize: lane's O rows are q = l4g*4+r
  float lb[4];
#pragma unroll
  for (int r = 0; r < 4; ++r) lb[r] = 1.f / __shfl(lr, l4g * 4 + r);
  short* __restrict__ ob = oT + (size_t)b * LSEQ * CCH;
#pragma unroll
  for (int df = 0; df < 4; ++df)
#pragma unroll
    for (int r = 0; r < 4; ++r)
      ob[(size_t)(l0 + wq + l4g * 4 + r) * CCH + h64 + df * 16 + l15] = f2bf(o[df][r] * lb[r]);
}

// ---------------- proj GEMM + bias + residual -> fp32 out -------------------
__global__ __launch_bounds__(256) void proj_gemm(
    const short* __restrict__ Wb, const float* __restrict__ bias,
    const short* __restrict__ oT, const float* __restrict__ x,
    float* __restrict__ out)
{
  const int b = blockIdx.z;
  const int m0 = blockIdx.y * 128, n0 = blockIdx.x * 128;
  const short* __restrict__ Bsrc = oT + (size_t)b * LSEQ * CCH;

  __shared__ short smem[32768];
  const int tid = threadIdx.x, lane = tid & 63, w = tid >> 6;
  const int wm = (w >> 1) * 64, wn = (w & 1) * 64;
  const int l15 = lane & 15, l4g = lane >> 4;
  const int sr = lane >> 3, c8 = ((lane & 7) ^ (lane >> 3)) * 8;
  const int swz = (l15 & 7) << 4;

  const f32x4 fz = {0.f, 0.f, 0.f, 0.f};
  f32x4 acc[4][4];
#pragma unroll
  for (int i = 0; i < 4; ++i)
#pragma unroll
    for (int j = 0; j < 4; ++j) acc[i][j] = fz;

#define PSTAGE(ks, bb)                                                        \
  {                                                                           \
    const int k0_ = (ks) * 64;                                                \
    _Pragma("unroll")                                                         \
    for (int i_ = 0; i_ < 4; ++i_) {                                          \
      const int rb_ = w * 32 + i_ * 8;                                        \
      gl2lds16(Wb   + (size_t)(m0 + rb_ + sr) * CCH + k0_ + c8,               \
               &smem[(bb) * 8192 + rb_ * 64]);                                \
      gl2lds16(Bsrc + (size_t)(n0 + rb_ + sr) * CCH + k0_ + c8,               \
               &smem[16384 + (bb) * 8192 + rb_ * 64]);                        \
    }                                                                         \
  }

  PSTAGE(0, 0);
  VMCNT0();
  __syncthreads();

  for (int ks = 0; ks < 8; ++ks) {
    const int bb = ks & 1;
    if (ks < 7) PSTAGE(ks + 1, bb ^ 1);
#pragma unroll
    for (int kk = 0; kk < 2; ++kk) {
      const int ko = (kk * 64 + l4g * 16) ^ swz;
      short8 af[4], bf[4];
#pragma unroll
      for (int i = 0; i < 4; ++i)
        af[i] = *(const short8*)((const char*)&smem[bb * 8192 + (wm + i * 16 + l15) * 64] + ko);
#pragma unroll
      for (int j = 0; j < 4; ++j)
        bf[j] = *(const short8*)((const char*)&smem[16384 + bb * 8192 + (wn + j * 16 + l15) * 64] + ko);
#pragma unroll
      for (int i = 0; i < 4; ++i)
#pragma unroll
        for (int j = 0; j < 4; ++j)
          acc[i][j] = MFMA(af[i], bf[j], acc[i][j], 0, 0, 0);
    }
    VMCNT0();
    __syncthreads();
  }

  const size_t obase = (size_t)b * CCH * LSEQ;
#pragma unroll
  for (int i = 0; i < 4; ++i)
#pragma unroll
    for (int r = 0; r < 4; ++r) {
      const int gm = m0 + wm + i * 16 + l4g * 4 + r;
      const float bb = bias[gm];
#pragma unroll
      for (int j = 0; j < 4; ++j) {
        const int gl = n0 + wn + j * 16 + l15;
        const size_t idx = obase + (size_t)gm * LSEQ + gl;
        out[idx] = acc[i][j][r] + bb + x[idx];
      }
    }
}

// ---------------------------------------------------------------------------
extern "C" void kernel_launch(void* const* d_in, const int* in_sizes, int n_in,
                              void* d_out, int out_size, void* d_ws, size_t ws_size,
                              hipStream_t stream)
{
  const float* x      = (const float*)d_in[0];
  const float* norm_w = (const float*)d_in[1];
  const float* norm_b = (const float*)d_in[2];
  const float* qkv_w  = (const float*)d_in[3];
  const float* qkv_b  = (const float*)d_in[4];
  const float* proj_w = (const float*)d_in[5];
  const float* proj_b = (const float*)d_in[6];
  float* out = (float*)d_out;

  char* ws = (char*)d_ws;
  short* wq16 = (short*)ws;                                   // 1536*512*2 = 1.5M
  short* wp16 = (short*)(ws + 1572864);                       // 512*512*2  = 0.5M
  short* hT   = (short*)(ws + 2097152);                       // 16M
  short* qT   = (short*)(ws + 2097152 + 16777216);            // 16M
  short* kT   = (short*)(ws + 2097152 + 2 * 16777216);        // 16M
  short* vv   = (short*)(ws + 2097152 + 3 * 16777216);        // 16M
  short* oT   = (short*)(ws + 2097152 + 4 * 16777216);        // 16M

  cvt_kernel<<<768, 256, 0, stream>>>(qkv_w, wq16);
  cvt_kernel<<<256, 256, 0, stream>>>(proj_w, wp16);
  gn_kernel<<<dim3(NG, BATCH), 256, 0, stream>>>(x, norm_w, norm_b, hT);
  qkv_gemm<<<dim3(8, 12, BATCH), 256, 0, stream>>>(wq16, qkv_b, hT, qT, kT, vv);
  attn_kernel<<<2048, 256, 0, stream>>>(qT, kT, vv, oT);
  proj_gemm<<<dim3(8, 4, BATCH), 256, 0, stream>>>(wp16, proj_b, oT, x, out);
}